// Round 1
// baseline (469.189 us; speedup 1.0000x reference)
//
#include <hip/hip_runtime.h>
#include <math.h>

// Problem constants
// B=8, W=32, H=32, C=64, NH=8, S=W*H=1024, O=NH*C=512, P(emb)=32, center=31
constexpr int CENTER = 31;

// =====================================================================
// Kernel 1: Q/K projections.
//   q[b,h,p,d] = (hidden[b,p,:] . Wq[h*64+d,:] + bq[h*64+d]) * 0.125  (scale folded)
//   k[b,h,p,d] =  hidden[b,p,:] . Wk[h*64+d,:] + bk[h*64+d]
// grid = 256 blocks (32 positions each), block = 512 threads
// threads 0-255 compute q, 256-511 compute k (wave-uniform split).
// =====================================================================
__global__ __launch_bounds__(512)
void qk_proj_kernel(const float* __restrict__ hid,
                    const float* __restrict__ Wq, const float* __restrict__ bq,
                    const float* __restrict__ Wk, const float* __restrict__ bk,
                    float* __restrict__ q_ws, float* __restrict__ k_ws)
{
    __shared__ float hs[32][64];     // hidden tile (reads are wave-broadcast)
    __shared__ float Wqs[64][65];    // +1 pad -> conflict-free tx-strided reads
    __shared__ float Wks[64][65];

    const int t  = threadIdx.x;
    const int g0 = blockIdx.x * 32;      // global position base
    const int b  = g0 >> 10;
    const int p0 = g0 & 1023;

    // stage hidden tile: 32x64 floats, one float4 per thread
    {
        int pl = t >> 4, c4 = (t & 15) << 2;
        float4 v = *(const float4*)(hid + (size_t)(g0 + pl) * 64 + c4);
        hs[pl][c4 + 0] = v.x; hs[pl][c4 + 1] = v.y;
        hs[pl][c4 + 2] = v.z; hs[pl][c4 + 3] = v.w;
    }

    const int path = t >> 8;         // 0 = q, 1 = k  (wave-uniform)
    const int t2 = t & 255;
    const int tx = t2 & 63;          // output dim within chunk (= d)
    const int ty = t2 >> 6;          // position group (8 positions each)

    const float* Wsel = path ? Wk : Wq;
    const float* bsel = path ? bk : bq;
    float*       osel = path ? k_ws : q_ws;
    float (* __restrict__ Wsh)[65] = path ? Wks : Wqs;

    for (int oc = 0; oc < 8; ++oc) {     // oc == head index (chunk size 64 == C)
        __syncthreads();
        // stage W chunk 64x64 (each path loads its own)
        {
            int row = t2 >> 2, off = (t2 & 3) << 4;
            const float* src = Wsel + (size_t)(oc * 64 + row) * 64 + off;
            #pragma unroll
            for (int u = 0; u < 4; ++u) {
                float4 v = *(const float4*)(src + 4 * u);
                Wsh[row][off + 4*u + 0] = v.x; Wsh[row][off + 4*u + 1] = v.y;
                Wsh[row][off + 4*u + 2] = v.z; Wsh[row][off + 4*u + 3] = v.w;
            }
        }
        __syncthreads();

        float acc[8] = {0.f,0.f,0.f,0.f,0.f,0.f,0.f,0.f};
        #pragma unroll 8
        for (int kk = 0; kk < 64; ++kk) {
            float wv = Wsh[tx][kk];
            #pragma unroll
            for (int r = 0; r < 8; ++r)
                acc[r] += hs[ty * 8 + r][kk] * wv;
        }

        float bias = bsel[oc * 64 + tx];
        #pragma unroll
        for (int r = 0; r < 8; ++r) {
            int p = p0 + ty * 8 + r;
            float val = acc[r] + bias;
            if (path == 0) val *= 0.125f;   // fold 1/sqrt(C)
            osel[(((size_t)b * 8 + oc) * 1024 + p) * 64 + tx] = val;
        }
    }
}

// =====================================================================
// Kernel 2: flash-style attention with decomposed positional bias.
// grid = (16 query tiles, 64 bh), block = 256 threads.
// Per block: 64 queries x 1024 keys, head dim 64, V = hidden (C=64).
// Online softmax state (m,l,alpha) kept in registers, replicated across
// the 16 lanes of each query group (identical via shfl butterflies).
// =====================================================================
__global__ __launch_bounds__(256, 2)
void attn_kernel(const float* __restrict__ q_ws, const float* __restrict__ k_ws,
                 const float* __restrict__ hid,
                 const float* __restrict__ row_emb, const float* __restrict__ col_emb,
                 float* __restrict__ mixed_ws)
{
    __shared__ float Qs[64][68];     // Q tile     (stride 68: 16B-aligned rows, 2-way max)
    __shared__ float KPs[64][68];    // K chunk, later aliased as P
    __shared__ float Hs[64][68];     // hidden (=V) chunk
    __shared__ float colb[64][33];   // col bias: [query][l]  (all 32 l needed each chunk)
    __shared__ float rowb2[64][2];   // row bias: only 2 key-rows per chunk

    const int t  = threadIdx.x;
    const int qt = blockIdx.x;       // 0..15
    const int bh = blockIdx.y;       // 0..63
    const int b  = bh >> 3, h = bh & 7;
    const int q0 = qt * 64;

    const float* qbase = q_ws + ((size_t)bh * 1024 + q0) * 64;
    const float* kbase = k_ws + (size_t)bh * 1024 * 64;
    const float* hbase = hid  + (size_t)b  * 1024 * 64;

    // stage Q tile (64x64), 4 float4 per thread
    #pragma unroll
    for (int u = 0; u < 4; ++u) {
        int idx4 = t + 256 * u;
        int row = idx4 >> 4, c4 = (idx4 & 15) << 2;
        *(float4*)&Qs[row][c4] = *(const float4*)(qbase + row * 64 + c4);
    }
    __syncthreads();

    // col bias: colb[qi][l] = q_col . col_emb[l - j + 31]   (q already scaled)
    for (int idx = t; idx < 64 * 32; idx += 256) {
        int qi = idx >> 5, l = idx & 31;
        int jq = qi & 31;                       // (q0+qi)%32 == qi%32 (q0 % 64 == 0)
        const float* ce = col_emb + (size_t)(l - jq + CENTER) * 32;
        float s2 = 0.f;
        #pragma unroll
        for (int d = 0; d < 32; ++d) s2 += Qs[qi][32 + d] * ce[d];
        colb[qi][l] = s2;
    }

    const int qg = t >> 4;       // query group: rows qg*4 .. qg*4+3
    const int kg = t & 15;       // key lane (QK) / d-group (PV)
    const int d0 = kg << 2;

    float m_reg[4], l_reg[4], acc[4][4];
    #pragma unroll
    for (int r = 0; r < 4; ++r) {
        m_reg[r] = -1e30f; l_reg[r] = 0.f;
        #pragma unroll
        for (int c = 0; c < 4; ++c) acc[r][c] = 0.f;
    }

    for (int kc = 0; kc < 16; ++kc) {
        __syncthreads();   // previous chunk fully consumed KPs/Hs/rowb2

        // stage K chunk + hidden chunk (4 float4 each per thread)
        #pragma unroll
        for (int u = 0; u < 4; ++u) {
            int idx4 = t + 256 * u;
            int row = idx4 >> 4, c4 = (idx4 & 15) << 2;
            *(float4*)&KPs[row][c4] = *(const float4*)(kbase + (size_t)(kc * 64 + row) * 64 + c4);
            *(float4*)&Hs[row][c4]  = *(const float4*)(hbase + (size_t)(kc * 64 + row) * 64 + c4);
        }
        // row bias for this chunk's 2 key rows
        if (t < 128) {
            int qi = t >> 1, kr = t & 1;
            int kglob = kc * 2 + kr;
            int iq = (q0 + qi) >> 5;
            const float* re = row_emb + (size_t)(kglob - iq + CENTER) * 32;
            float s1 = 0.f;
            #pragma unroll
            for (int d = 0; d < 32; ++d) s1 += Qs[qi][d] * re[d];
            rowb2[qi][kr] = s1;
        }
        __syncthreads();

        // ---- scores: s[rq][rk], keys ki = kg + 16*rk ----
        float s[4][4];
        #pragma unroll
        for (int rq = 0; rq < 4; ++rq) {
            int qi = qg * 4 + rq;
            float rb0 = rowb2[qi][0];
            float rb1 = rowb2[qi][1];
            float cb0 = colb[qi][kg];
            float cb1 = colb[qi][kg + 16];
            s[rq][0] = rb0 + cb0;   // ki = kg      -> row 0, col kg
            s[rq][1] = rb0 + cb1;   // ki = kg+16   -> row 0, col kg+16
            s[rq][2] = rb1 + cb0;   // ki = kg+32   -> row 1, col kg
            s[rq][3] = rb1 + cb1;   // ki = kg+48   -> row 1, col kg+16
        }
        #pragma unroll 8
        for (int d4 = 0; d4 < 64; d4 += 4) {
            float4 qv[4], kv[4];
            #pragma unroll
            for (int r = 0; r < 4; ++r) qv[r] = *(const float4*)&Qs[qg * 4 + r][d4];
            #pragma unroll
            for (int r = 0; r < 4; ++r) kv[r] = *(const float4*)&KPs[kg + 16 * r][d4];
            #pragma unroll
            for (int rq = 0; rq < 4; ++rq)
                #pragma unroll
                for (int rk = 0; rk < 4; ++rk)
                    s[rq][rk] += qv[rq].x * kv[rk].x + qv[rq].y * kv[rk].y
                               + qv[rq].z * kv[rk].z + qv[rq].w * kv[rk].w;
        }

        // ---- online softmax (register state, replicated across 16 lanes) ----
        float p[4][4];
        float alpha[4];
        #pragma unroll
        for (int rq = 0; rq < 4; ++rq) {
            float cm = fmaxf(fmaxf(s[rq][0], s[rq][1]), fmaxf(s[rq][2], s[rq][3]));
            #pragma unroll
            for (int off = 1; off < 16; off <<= 1)
                cm = fmaxf(cm, __shfl_xor(cm, off));
            float mnew = fmaxf(m_reg[rq], cm);
            alpha[rq] = __expf(m_reg[rq] - mnew);
            float rs = 0.f;
            #pragma unroll
            for (int rk = 0; rk < 4; ++rk) {
                p[rq][rk] = __expf(s[rq][rk] - mnew);
                rs += p[rq][rk];
            }
            #pragma unroll
            for (int off = 1; off < 16; off <<= 1)
                rs += __shfl_xor(rs, off);
            l_reg[rq] = l_reg[rq] * alpha[rq] + rs;
            m_reg[rq] = mnew;
            #pragma unroll
            for (int c = 0; c < 4; ++c) acc[rq][c] *= alpha[rq];
        }

        __syncthreads();   // all lanes done reading KPs as K
        // write P into the K buffer: Ps[qi][ki]
        #pragma unroll
        for (int rq = 0; rq < 4; ++rq)
            #pragma unroll
            for (int rk = 0; rk < 4; ++rk)
                KPs[qg * 4 + rq][kg + 16 * rk] = p[rq][rk];
        __syncthreads();

        // ---- PV: acc[rq][c] += sum_k P[qi][k] * Hs[k][d0+c] ----
        #pragma unroll 8
        for (int k4 = 0; k4 < 64; k4 += 4) {
            float4 pv[4], hv[4];
            #pragma unroll
            for (int r = 0; r < 4; ++r) pv[r] = *(const float4*)&KPs[qg * 4 + r][k4];
            #pragma unroll
            for (int kk = 0; kk < 4; ++kk) hv[kk] = *(const float4*)&Hs[k4 + kk][d0];
            #pragma unroll
            for (int rq = 0; rq < 4; ++rq) {
                acc[rq][0] += pv[rq].x * hv[0].x + pv[rq].y * hv[1].x + pv[rq].z * hv[2].x + pv[rq].w * hv[3].x;
                acc[rq][1] += pv[rq].x * hv[0].y + pv[rq].y * hv[1].y + pv[rq].z * hv[2].y + pv[rq].w * hv[3].y;
                acc[rq][2] += pv[rq].x * hv[0].z + pv[rq].y * hv[1].z + pv[rq].z * hv[2].z + pv[rq].w * hv[3].z;
                acc[rq][3] += pv[rq].x * hv[0].w + pv[rq].y * hv[1].w + pv[rq].z * hv[2].w + pv[rq].w * hv[3].w;
            }
        }
    }

    // epilogue: normalize and store mixed[b][p][h][d]
    #pragma unroll
    for (int rq = 0; rq < 4; ++rq) {
        float inv = 1.0f / l_reg[rq];
        int p = q0 + qg * 4 + rq;
        float4 v;
        v.x = acc[rq][0] * inv; v.y = acc[rq][1] * inv;
        v.z = acc[rq][2] * inv; v.w = acc[rq][3] * inv;
        *(float4*)(mixed_ws + (((size_t)b * 1024 + p) * 8 + h) * 64 + d0) = v;
    }
}

// =====================================================================
// Kernel 3: output projection. out[g][c] = sum_o mixed[g][o]*Wv[c][o] + bv[c]
// grid = 256 blocks (32 positions each), block = 256 threads.
// =====================================================================
__global__ __launch_bounds__(256)
void out_proj_kernel(const float* __restrict__ mixed_ws,
                     const float* __restrict__ Wv, const float* __restrict__ bv,
                     float* __restrict__ out)
{
    __shared__ float mx[32][64];
    __shared__ float Wvs[64][65];

    const int t  = threadIdx.x;
    const int g0 = blockIdx.x * 32;
    const int tx = t & 63;        // output channel c
    const int ty = t >> 6;        // position group (8 each)

    float acc[8] = {0.f,0.f,0.f,0.f,0.f,0.f,0.f,0.f};

    for (int oc = 0; oc < 8; ++oc) {
        __syncthreads();
        // stage mixed chunk 32x64
        #pragma unroll
        for (int u = 0; u < 2; ++u) {
            int idx4 = t + 256 * u;
            int row = idx4 >> 4, c4 = (idx4 & 15) << 2;
            *(float4*)&mx[row][c4] =
                *(const float4*)(mixed_ws + (size_t)(g0 + row) * 512 + oc * 64 + c4);
        }
        // stage Wv chunk 64x64: Wvs[c][oo] = Wv[c*512 + oc*64 + oo]
        {
            int row = t >> 2, off = (t & 3) << 4;
            const float* src = Wv + (size_t)row * 512 + oc * 64 + off;
            #pragma unroll
            for (int u = 0; u < 4; ++u) {
                float4 v = *(const float4*)(src + 4 * u);
                Wvs[row][off + 4*u + 0] = v.x; Wvs[row][off + 4*u + 1] = v.y;
                Wvs[row][off + 4*u + 2] = v.z; Wvs[row][off + 4*u + 3] = v.w;
            }
        }
        __syncthreads();

        #pragma unroll 8
        for (int oo = 0; oo < 64; ++oo) {
            float wv = Wvs[tx][oo];
            #pragma unroll
            for (int r = 0; r < 8; ++r)
                acc[r] += mx[ty * 8 + r][oo] * wv;
        }
    }

    float bias = bv[tx];
    #pragma unroll
    for (int r = 0; r < 8; ++r)
        out[(size_t)(g0 + ty * 8 + r) * 64 + tx] = acc[r] + bias;
}

// =====================================================================
extern "C" void kernel_launch(void* const* d_in, const int* in_sizes, int n_in,
                              void* d_out, int out_size, void* d_ws, size_t ws_size,
                              hipStream_t stream)
{
    const float* hid     = (const float*)d_in[0];   // (8,32,32,64)
    const float* row_emb = (const float*)d_in[1];   // (63,32)
    const float* col_emb = (const float*)d_in[2];   // (63,32)
    const float* Wq      = (const float*)d_in[3];   // (512,64)
    const float* bq      = (const float*)d_in[4];   // (512,)
    const float* Wk      = (const float*)d_in[5];   // (512,64)
    const float* bk      = (const float*)d_in[6];   // (512,)
    const float* Wv      = (const float*)d_in[7];   // (64,512)
    const float* bv      = (const float*)d_in[8];   // (64,)
    float* out = (float*)d_out;

    // workspace layout: q (16MB) | k (16MB) | mixed (16MB)
    float* q_ws     = (float*)d_ws;
    float* k_ws     = q_ws + (size_t)8 * 8 * 1024 * 64;
    float* mixed_ws = k_ws + (size_t)8 * 8 * 1024 * 64;

    qk_proj_kernel<<<256, 512, 0, stream>>>(hid, Wq, bq, Wk, bk, q_ws, k_ws);
    attn_kernel<<<dim3(16, 64), 256, 0, stream>>>(q_ws, k_ws, hid, row_emb, col_emb, mixed_ws);
    out_proj_kernel<<<256, 256, 0, stream>>>(mixed_ws, Wv, bv, out);
}

// Round 2
// 211.180 us; speedup vs baseline: 2.2218x; 2.2218x over previous
//
#include <hip/hip_runtime.h>
#include <math.h>

typedef __bf16 bf16;
typedef bf16 bf16x8 __attribute__((ext_vector_type(8)));
typedef float f32x4 __attribute__((ext_vector_type(4)));

constexpr int CENTER = 31;

static __device__ __forceinline__ unsigned short f2bf_bits(float f) {
    bf16 b = (bf16)f;
    return __builtin_bit_cast(unsigned short, b);
}

// =====================================================================
// Kernel 1: Q/K projections (fp32 math, bf16 outputs) + hidden^T bf16.
//   qb[bh][pos][d] = ((hid[pos,:] . Wq[h*64+d,:]) + bq) * 0.125   (scale folded)
//   kb[bh][pos][d] =  (hid[pos,:] . Wk[h*64+d,:]) + bk
//   htb[b][d][pos] =  hid[b,pos,d]   (transposed, bf16 — V operand for PV MFMA)
// grid = 256 blocks (32 positions each), block = 512 threads (path split q/k).
// =====================================================================
__global__ __launch_bounds__(512)
void qk_proj_kernel(const float* __restrict__ hid,
                    const float* __restrict__ Wq, const float* __restrict__ bq,
                    const float* __restrict__ Wk, const float* __restrict__ bk,
                    bf16* __restrict__ qb, bf16* __restrict__ kb,
                    bf16* __restrict__ htb)
{
    __shared__ float hs[32][64];
    __shared__ float Wqs[64][65];
    __shared__ float Wks[64][65];

    const int t  = threadIdx.x;
    const int g0 = blockIdx.x * 32;
    const int b  = g0 >> 10;
    const int p0 = g0 & 1023;

    // stage hidden tile: 32x64 floats, one float4 per thread (first 512... 512 thr, 512 float4 slots /4)
    {
        int pl = t >> 4, c4 = (t & 15) << 2;
        if (t < 512) { // 32*16 = 512 exactly
            float4 v = *(const float4*)(hid + (size_t)(g0 + pl) * 64 + c4);
            hs[pl][c4 + 0] = v.x; hs[pl][c4 + 1] = v.y;
            hs[pl][c4 + 2] = v.z; hs[pl][c4 + 3] = v.w;
        }
    }
    __syncthreads();

    // hidden^T bf16 write: thread t -> d = t>>3, positions (t&7)*4 .. +3
    {
        int d = t >> 3, p4 = (t & 7) << 2;
        ushort4 pk;
        pk.x = f2bf_bits(hs[p4 + 0][d]);
        pk.y = f2bf_bits(hs[p4 + 1][d]);
        pk.z = f2bf_bits(hs[p4 + 2][d]);
        pk.w = f2bf_bits(hs[p4 + 3][d]);
        *(ushort4*)(htb + ((size_t)b * 64 + d) * 1024 + p0 + p4) = pk;
    }

    const int path = t >> 8;         // 0 = q, 1 = k (wave-uniform)
    const int t2 = t & 255;
    const int tx = t2 & 63;          // d
    const int ty = t2 >> 6;          // position group (8 each)

    const float* Wsel = path ? Wk : Wq;
    const float* bsel = path ? bk : bq;
    bf16*        osel = path ? kb : qb;
    float (* __restrict__ Wsh)[65] = path ? Wks : Wqs;

    for (int oc = 0; oc < 8; ++oc) {     // oc == head
        __syncthreads();
        {
            int row = t2 >> 2, off = (t2 & 3) << 4;
            const float* src = Wsel + (size_t)(oc * 64 + row) * 64 + off;
            #pragma unroll
            for (int u = 0; u < 4; ++u) {
                float4 v = *(const float4*)(src + 4 * u);
                Wsh[row][off + 4*u + 0] = v.x; Wsh[row][off + 4*u + 1] = v.y;
                Wsh[row][off + 4*u + 2] = v.z; Wsh[row][off + 4*u + 3] = v.w;
            }
        }
        __syncthreads();

        float acc[8] = {0.f,0.f,0.f,0.f,0.f,0.f,0.f,0.f};
        #pragma unroll 8
        for (int kk = 0; kk < 64; ++kk) {
            float wv = Wsh[tx][kk];
            #pragma unroll
            for (int r = 0; r < 8; ++r)
                acc[r] += hs[ty * 8 + r][kk] * wv;
        }

        float bias = bsel[oc * 64 + tx];
        float scale = path ? 1.0f : 0.125f;
        #pragma unroll
        for (int r = 0; r < 8; ++r) {
            int p = p0 + ty * 8 + r;
            float val = (acc[r] + bias) * scale;
            osel[(((size_t)b * 8 + oc) * 1024 + p) * 64 + tx] = (bf16)val;
        }
    }
}

// =====================================================================
// Kernel 2: MFMA flash attention (no max-rescale: |scores| << 80).
// grid = (16 q-tiles, 64 bh), block = 256 (4 waves).
// Wave w: q rows w*16..w*16+15 x all 1024 keys, 16x16x32 bf16 MFMA.
//   scores = q'.k + rowbias + colbias   (q pre-scaled by 1/8)
//   P round-trips via per-wave LDS (C-layout -> A-layout, m120 pattern).
// =====================================================================
__global__ __launch_bounds__(256, 3)
void attn_kernel(const bf16* __restrict__ qb, const bf16* __restrict__ kb,
                 const bf16* __restrict__ htb,
                 const float* __restrict__ row_emb, const float* __restrict__ col_emb,
                 float* __restrict__ mixed_ws)
{
    __shared__ __attribute__((aligned(16))) bf16 Qs[64][72];
    __shared__ __attribute__((aligned(16))) union {
        struct { bf16 Ks[64][72]; bf16 Hts[64][72]; } s;   // 18432 B
        float emb[2 * 63 * 32];                             // 16128 B (preamble only)
    } u;
    __shared__ __attribute__((aligned(16))) bf16 Ps[4][16][72];
    __shared__ float colb[64][34];
    __shared__ float rowb[64][34];

    const int t  = threadIdx.x;
    const int qt = blockIdx.x;       // 0..15
    const int bh = blockIdx.y;       // 0..63
    const int b  = bh >> 3, h = bh & 7;
    const int q0 = qt * 64;
    const int w    = t >> 6;
    const int ln   = t & 63;
    const int l15  = ln & 15;
    const int quad = ln >> 4;

    // ---- stage Q tile (64x64 bf16) + both embeddings ----
    {
        int row = t >> 2, c = (t & 3) << 4;
        const int4* src = (const int4*)(qb + ((size_t)bh * 1024 + q0 + row) * 64 + c);
        *(int4*)&Qs[row][c]     = src[0];
        *(int4*)&Qs[row][c + 8] = src[1];
    }
    {
        float2* dst = (float2*)u.emb;
        const float2* re2 = (const float2*)row_emb;
        const float2* ce2 = (const float2*)col_emb;
        for (int i = t; i < 1008; i += 256) dst[i] = re2[i];
        for (int i = t; i < 1008; i += 256) dst[1008 + i] = ce2[i];
    }
    __syncthreads();

    // ---- biases (fp32, once per block): thread -> qi = t>>2, 8 l / 8 kr ----
    {
        int qi = t >> 2, oct = t & 3;
        int jq = qi & 31;
        int iq = qt * 2 + (qi >> 5);
        float qv[32];
        // col half of q
        #pragma unroll
        for (int j = 0; j < 4; ++j) {
            bf16x8 v = *(const bf16x8*)&Qs[qi][32 + j * 8];
            #pragma unroll
            for (int e = 0; e < 8; ++e) qv[j * 8 + e] = (float)v[e];
        }
        #pragma unroll
        for (int i = 0; i < 8; ++i) {
            int l = oct * 8 + i;
            const float* e = &u.emb[2016 + (l - jq + CENTER) * 32];
            float s = 0.f;
            #pragma unroll
            for (int d = 0; d < 32; d += 4) {
                float4 ev = *(const float4*)(e + d);
                s += qv[d] * ev.x + qv[d+1] * ev.y + qv[d+2] * ev.z + qv[d+3] * ev.w;
            }
            colb[qi][l] = s;
        }
        // row half of q
        #pragma unroll
        for (int j = 0; j < 4; ++j) {
            bf16x8 v = *(const bf16x8*)&Qs[qi][j * 8];
            #pragma unroll
            for (int e = 0; e < 8; ++e) qv[j * 8 + e] = (float)v[e];
        }
        #pragma unroll
        for (int i = 0; i < 8; ++i) {
            int kr = oct * 8 + i;
            const float* e = &u.emb[(kr - iq + CENTER) * 32];
            float s = 0.f;
            #pragma unroll
            for (int d = 0; d < 32; d += 4) {
                float4 ev = *(const float4*)(e + d);
                s += qv[d] * ev.x + qv[d+1] * ev.y + qv[d+2] * ev.z + qv[d+3] * ev.w;
            }
            rowb[qi][kr] = s;
        }
    }
    __syncthreads();

    // ---- loop-invariant register preloads ----
    float cb[4][2];
    #pragma unroll
    for (int r = 0; r < 4; ++r) {
        cb[r][0] = colb[w * 16 + quad * 4 + r][l15];
        cb[r][1] = colb[w * 16 + quad * 4 + r][16 + l15];
    }
    bf16x8 aq0 = *(const bf16x8*)&Qs[w * 16 + l15][quad * 8];
    bf16x8 aq1 = *(const bf16x8*)&Qs[w * 16 + l15][32 + quad * 8];

    const f32x4 zero4 = {0.f, 0.f, 0.f, 0.f};
    f32x4 oacc[4] = {zero4, zero4, zero4, zero4};
    float lsum[4] = {0.f, 0.f, 0.f, 0.f};
    bf16* Pw = &Ps[w][0][0];

    for (int kc = 0; kc < 16; ++kc) {
        __syncthreads();   // previous chunk consumed (and at kc=0: bias phase done with u.emb)
        // stage K chunk (row-major) and H^T chunk (d-major), 32 B per thread each
        {
            int row = t >> 2, c = (t & 3) << 4;
            const int4* ks = (const int4*)(kb + ((size_t)bh * 1024 + kc * 64 + row) * 64 + c);
            *(int4*)&u.s.Ks[row][c]     = ks[0];
            *(int4*)&u.s.Ks[row][c + 8] = ks[1];
            const int4* hsrc = (const int4*)(htb + ((size_t)b * 64 + row) * 1024 + kc * 64 + c);
            *(int4*)&u.s.Hts[row][c]     = hsrc[0];
            *(int4*)&u.s.Hts[row][c + 8] = hsrc[1];
        }
        __syncthreads();

        // ---- QK^T: 4 key-tiles x (k=64 via 2 MFMAs) ----
        f32x4 sf[4] = {zero4, zero4, zero4, zero4};
        #pragma unroll
        for (int kt = 0; kt < 4; ++kt) {
            bf16x8 bk0 = *(const bf16x8*)&u.s.Ks[kt * 16 + l15][quad * 8];
            bf16x8 bk1 = *(const bf16x8*)&u.s.Ks[kt * 16 + l15][32 + quad * 8];
            sf[kt] = __builtin_amdgcn_mfma_f32_16x16x32_bf16(aq0, bk0, sf[kt], 0, 0, 0);
            sf[kt] = __builtin_amdgcn_mfma_f32_16x16x32_bf16(aq1, bk1, sf[kt], 0, 0, 0);
        }

        // ---- bias add + exp + row-sum + P write (C-layout -> LDS) ----
        float2 rb[4];
        #pragma unroll
        for (int r = 0; r < 4; ++r)
            rb[r] = *(const float2*)&rowb[w * 16 + quad * 4 + r][kc * 2];
        #pragma unroll
        for (int kt = 0; kt < 4; ++kt) {
            #pragma unroll
            for (int r = 0; r < 4; ++r) {
                float s = sf[kt][r] + ((kt & 2) ? rb[r].y : rb[r].x) + cb[r][kt & 1];
                float p = __expf(s);
                lsum[r] += p;
                Pw[(quad * 4 + r) * 72 + kt * 16 + l15] = (bf16)p;
            }
        }

        // ---- PV: O[q][d] += P[q][k] * H[k][d]  (A=P from LDS, B=H^T frags) ----
        bf16x8 ap0 = *(const bf16x8*)&Pw[l15 * 72 + quad * 8];
        bf16x8 ap1 = *(const bf16x8*)&Pw[l15 * 72 + 32 + quad * 8];
        #pragma unroll
        for (int dt = 0; dt < 4; ++dt) {
            bf16x8 bh0 = *(const bf16x8*)&u.s.Hts[dt * 16 + l15][quad * 8];
            bf16x8 bh1 = *(const bf16x8*)&u.s.Hts[dt * 16 + l15][32 + quad * 8];
            oacc[dt] = __builtin_amdgcn_mfma_f32_16x16x32_bf16(ap0, bh0, oacc[dt], 0, 0, 0);
            oacc[dt] = __builtin_amdgcn_mfma_f32_16x16x32_bf16(ap1, bh1, oacc[dt], 0, 0, 0);
        }
    }

    // ---- epilogue: reduce l over the 16 key-lanes, normalize, store ----
    #pragma unroll
    for (int r = 0; r < 4; ++r) {
        float v = lsum[r];
        v += __shfl_xor(v, 1);
        v += __shfl_xor(v, 2);
        v += __shfl_xor(v, 4);
        v += __shfl_xor(v, 8);
        lsum[r] = 1.0f / v;
    }
    #pragma unroll
    for (int dt = 0; dt < 4; ++dt) {
        #pragma unroll
        for (int r = 0; r < 4; ++r) {
            int pos = q0 + w * 16 + quad * 4 + r;
            mixed_ws[(((size_t)b * 1024 + pos) * 8 + h) * 64 + dt * 16 + l15] =
                oacc[dt][r] * lsum[r];
        }
    }
}

// =====================================================================
// Kernel 3: output projection (fp32). out[g][c] = mixed[g][:] . Wv[c][:] + bv[c]
// =====================================================================
__global__ __launch_bounds__(256)
void out_proj_kernel(const float* __restrict__ mixed_ws,
                     const float* __restrict__ Wv, const float* __restrict__ bv,
                     float* __restrict__ out)
{
    __shared__ float mx[32][64];
    __shared__ float Wvs[64][65];

    const int t  = threadIdx.x;
    const int g0 = blockIdx.x * 32;
    const int tx = t & 63;
    const int ty = t >> 6;

    float acc[8] = {0.f,0.f,0.f,0.f,0.f,0.f,0.f,0.f};

    for (int oc = 0; oc < 8; ++oc) {
        __syncthreads();
        #pragma unroll
        for (int u = 0; u < 2; ++u) {
            int idx4 = t + 256 * u;
            int row = idx4 >> 4, c4 = (idx4 & 15) << 2;
            *(float4*)&mx[row][c4] =
                *(const float4*)(mixed_ws + (size_t)(g0 + row) * 512 + oc * 64 + c4);
        }
        {
            int row = t >> 2, off = (t & 3) << 4;
            const float* src = Wv + (size_t)row * 512 + oc * 64 + off;
            #pragma unroll
            for (int u = 0; u < 4; ++u) {
                float4 v = *(const float4*)(src + 4 * u);
                Wvs[row][off + 4*u + 0] = v.x; Wvs[row][off + 4*u + 1] = v.y;
                Wvs[row][off + 4*u + 2] = v.z; Wvs[row][off + 4*u + 3] = v.w;
            }
        }
        __syncthreads();

        #pragma unroll 8
        for (int oo = 0; oo < 64; ++oo) {
            float wv = Wvs[tx][oo];
            #pragma unroll
            for (int r = 0; r < 8; ++r)
                acc[r] += mx[ty * 8 + r][oo] * wv;
        }
    }

    float bias = bv[tx];
    #pragma unroll
    for (int r = 0; r < 8; ++r)
        out[(size_t)(g0 + ty * 8 + r) * 64 + tx] = acc[r] + bias;
}

// =====================================================================
extern "C" void kernel_launch(void* const* d_in, const int* in_sizes, int n_in,
                              void* d_out, int out_size, void* d_ws, size_t ws_size,
                              hipStream_t stream)
{
    const float* hid     = (const float*)d_in[0];
    const float* row_emb = (const float*)d_in[1];
    const float* col_emb = (const float*)d_in[2];
    const float* Wq      = (const float*)d_in[3];
    const float* bq      = (const float*)d_in[4];
    const float* Wk      = (const float*)d_in[5];
    const float* bk      = (const float*)d_in[6];
    const float* Wv      = (const float*)d_in[7];
    const float* bv      = (const float*)d_in[8];
    float* out = (float*)d_out;

    // workspace: qb (8MB bf16) | kb (8MB bf16) | htb (1MB bf16) | mixed (16MB f32)
    bf16* qb  = (bf16*)d_ws;
    bf16* kb  = qb + (size_t)64 * 1024 * 64;
    bf16* htb = kb + (size_t)64 * 1024 * 64;
    float* mixed_ws = (float*)(htb + (size_t)8 * 64 * 1024);

    qk_proj_kernel<<<256, 512, 0, stream>>>(hid, Wq, bq, Wk, bk, qb, kb, htb);
    attn_kernel<<<dim3(16, 64), 256, 0, stream>>>(qb, kb, htb, row_emb, col_emb, mixed_ws);
    out_proj_kernel<<<256, 256, 0, stream>>>(mixed_ws, Wv, bv, out);
}

// Round 3
// 157.431 us; speedup vs baseline: 2.9803x; 1.3414x over previous
//
#include <hip/hip_runtime.h>
#include <math.h>

typedef __bf16 bf16;
typedef bf16 bf16x2 __attribute__((ext_vector_type(2)));
typedef bf16 bf16x8 __attribute__((ext_vector_type(8)));
typedef float f32x4 __attribute__((ext_vector_type(4)));

constexpr int CENTER = 31;

static __device__ __forceinline__ unsigned short f2bf_bits(float f) {
    bf16 b = (bf16)f;
    return __builtin_bit_cast(unsigned short, b);
}

// =====================================================================
// Kernel 1: Q/K projection GEMM via MFMA (bf16 in, bf16 out) + htb side-emit.
//   C[pos][o] = hid[pos,:] . W[o,:] (+bias) (*0.125 for q)
// grid = (64 pos-tiles x 4 out-tiles x {q,k}), block 256 (4 waves, 32 pos each).
// =====================================================================
__global__ __launch_bounds__(256)
void qkproj_kernel(const float* __restrict__ hid,
                   const float* __restrict__ Wq, const float* __restrict__ bq,
                   const float* __restrict__ Wk, const float* __restrict__ bk,
                   bf16* __restrict__ qb, bf16* __restrict__ kb,
                   bf16* __restrict__ htb)
{
    __shared__ __attribute__((aligned(16))) bf16 As[128][72];
    __shared__ __attribute__((aligned(16))) bf16 Bs[128][72];

    const int t  = threadIdx.x;
    const int pt = blockIdx.x;        // pos tile (128)
    const int ot = blockIdx.y;        // out tile (128 of 512)
    const int z  = blockIdx.z;        // 0=q, 1=k
    const float* W    = z ? Wk : Wq;
    const float* bias = z ? bk : bq;
    bf16* outp        = z ? kb : qb;
    const float scale = z ? 1.0f : 0.125f;
    const int p0 = pt * 128;
    const int b  = p0 >> 10;

    // stage A (hid) and B (W) tiles, fp32 -> bf16. 32 elems/thread each.
    {
        int row = t >> 1, ch = (t & 1) * 32;
        const float4* asrc = (const float4*)(hid + (size_t)(p0 + row) * 64 + ch);
        const float4* bsrc = (const float4*)(W + (size_t)(ot * 128 + row) * 64 + ch);
        bf16 ta[32], tb[32];
        #pragma unroll
        for (int u = 0; u < 8; ++u) {
            float4 va = asrc[u], vb = bsrc[u];
            ta[4*u+0] = (bf16)va.x; ta[4*u+1] = (bf16)va.y;
            ta[4*u+2] = (bf16)va.z; ta[4*u+3] = (bf16)va.w;
            tb[4*u+0] = (bf16)vb.x; tb[4*u+1] = (bf16)vb.y;
            tb[4*u+2] = (bf16)vb.z; tb[4*u+3] = (bf16)vb.w;
        }
        #pragma unroll
        for (int u = 0; u < 4; ++u) {
            *(int4*)&As[row][ch + u * 8] = ((int4*)ta)[u];
            *(int4*)&Bs[row][ch + u * 8] = ((int4*)tb)[u];
        }
    }
    __syncthreads();

    // side-emit hidden^T bf16 (once: ot==0, z==0 blocks)
    if (ot == 0 && z == 0) {
        int d = t >> 2, ps = (t & 3) * 32;
        bf16* hdst = htb + ((size_t)b * 64 + d) * 1024 + (p0 & 1023) + ps;
        #pragma unroll
        for (int ii = 0; ii < 32; ii += 2) {
            ushort2 pk;
            pk.x = __builtin_bit_cast(unsigned short, As[ps + ii][d]);
            pk.y = __builtin_bit_cast(unsigned short, As[ps + ii + 1][d]);
            *(ushort2*)(hdst + ii) = pk;
        }
    }

    const int w = t >> 6, ln = t & 63, l15 = ln & 15, quad = ln >> 4;

    bf16x8 a[2][2];
    #pragma unroll
    for (int mt = 0; mt < 2; ++mt) {
        a[mt][0] = *(const bf16x8*)&As[w * 32 + mt * 16 + l15][quad * 8];
        a[mt][1] = *(const bf16x8*)&As[w * 32 + mt * 16 + l15][32 + quad * 8];
    }

    const f32x4 z4 = {0.f, 0.f, 0.f, 0.f};
    f32x4 acc[2][8];
    #pragma unroll
    for (int mt = 0; mt < 2; ++mt)
        #pragma unroll
        for (int nt = 0; nt < 8; ++nt) acc[mt][nt] = z4;

    #pragma unroll
    for (int nt = 0; nt < 8; ++nt) {
        bf16x8 b0 = *(const bf16x8*)&Bs[nt * 16 + l15][quad * 8];
        bf16x8 b1 = *(const bf16x8*)&Bs[nt * 16 + l15][32 + quad * 8];
        #pragma unroll
        for (int mt = 0; mt < 2; ++mt) {
            acc[mt][nt] = __builtin_amdgcn_mfma_f32_16x16x32_bf16(a[mt][0], b0, acc[mt][nt], 0, 0, 0);
            acc[mt][nt] = __builtin_amdgcn_mfma_f32_16x16x32_bf16(a[mt][1], b1, acc[mt][nt], 0, 0, 0);
        }
    }

    #pragma unroll
    for (int nt = 0; nt < 8; ++nt) {
        int o = ot * 128 + nt * 16 + l15;
        float bv = bias[o];
        int hh = o >> 6, d = o & 63;
        #pragma unroll
        for (int mt = 0; mt < 2; ++mt)
            #pragma unroll
            for (int r = 0; r < 4; ++r) {
                int pos = (p0 & 1023) + w * 32 + mt * 16 + quad * 4 + r;
                float val = (acc[mt][nt][r] + bv) * scale;
                outp[(((size_t)b * 8 + hh) * 1024 + pos) * 64 + d] = (bf16)val;
            }
    }
}

// =====================================================================
// Kernel 2: positional-bias precompute via MFMA.
//   rowbias[bh][q][kr] = qrow[bh,q,:32] . row_emb[kr - (q>>5) + 31, :]
//   colbias[bh][q][l]  = qcol[bh,q,32:] . col_emb[l  - (q&31) + 31, :]
// grid (64 bh x 4 sg), block 256. Tiles of fixed i (row) / fixed j (col).
// =====================================================================
__global__ __launch_bounds__(256)
void bias_kernel(const bf16* __restrict__ qb,
                 const float* __restrict__ row_emb, const float* __restrict__ col_emb,
                 bf16* __restrict__ rowbias, bf16* __restrict__ colbias)
{
    __shared__ __attribute__((aligned(16))) bf16 embRs[63][40];
    __shared__ __attribute__((aligned(16))) bf16 embCs[63][40];

    const int t  = threadIdx.x;
    const int bh = blockIdx.x;
    const int sg = blockIdx.y;   // 0..3

    for (int i = t; i < 2016; i += 256) embRs[i >> 5][i & 31] = (bf16)row_emb[i];
    for (int i = t; i < 2016; i += 256) embCs[i >> 5][i & 31] = (bf16)col_emb[i];
    __syncthreads();

    const int w = t >> 6, ln = t & 63, l15 = ln & 15, quad = ln >> 4;

    #pragma unroll
    for (int u = 0; u < 4; ++u) {
        int s = sg * 16 + u * 4 + w;    // 0..63
        bool cm = s >= 32;              // col mode
        int ij = cm ? s - 32 : s;

        bf16x8 a[2];
        #pragma unroll
        for (int mt = 0; mt < 2; ++mt) {
            const bf16* ap = cm
                ? qb + ((size_t)bh * 1024 + (mt * 16 + l15) * 32 + ij) * 64 + 32 + quad * 8
                : qb + ((size_t)bh * 1024 + ij * 32 + mt * 16 + l15) * 64 + quad * 8;
            a[mt] = *(const bf16x8*)ap;
        }
        bf16* ob = cm ? colbias : rowbias;

        #pragma unroll
        for (int nt = 0; nt < 2; ++nt) {
            int erow = nt * 16 + l15 + CENTER - ij;   // in [0,62]
            bf16x8 bfrag = cm ? *(const bf16x8*)&embCs[erow][quad * 8]
                              : *(const bf16x8*)&embRs[erow][quad * 8];
            #pragma unroll
            for (int mt = 0; mt < 2; ++mt) {
                f32x4 c = {0.f, 0.f, 0.f, 0.f};
                c = __builtin_amdgcn_mfma_f32_16x16x32_bf16(a[mt], bfrag, c, 0, 0, 0);
                #pragma unroll
                for (int r = 0; r < 4; ++r) {
                    int ql = mt * 16 + quad * 4 + r;
                    int qrow = cm ? ql * 32 + ij : ij * 32 + ql;
                    ob[((size_t)bh * 1024 + qrow) * 32 + nt * 16 + l15] = (bf16)c[r];
                }
            }
        }
    }
}

// =====================================================================
// Kernel 3: MFMA flash attention (no max-rescale; biases preloaded).
// grid (8 q-tiles of 128, 64 bh), block 256 (4 waves x 32 q).
// P buffer: pitch 72, XOR-16-chunk swizzle keyed by (row>>2)&3 -> conflict-free
// writes AND b128-aligned reads.
// =====================================================================
__global__ __launch_bounds__(256, 3)
void attn_kernel(const bf16* __restrict__ qb, const bf16* __restrict__ kb,
                 const bf16* __restrict__ htb,
                 const bf16* __restrict__ rowbias, const bf16* __restrict__ colbias,
                 float* __restrict__ mixed_ws)
{
    __shared__ __attribute__((aligned(16))) bf16 Ks[64][72];
    __shared__ __attribute__((aligned(16))) bf16 Hts[64][72];
    __shared__ __attribute__((aligned(16))) bf16 Ps[4][32][72];
    __shared__ __attribute__((aligned(16))) bf16 rowbL[128][40];

    const int t  = threadIdx.x;
    const int qt = blockIdx.x;       // 0..7
    const int bh = blockIdx.y;       // 0..63
    const int b  = bh >> 3, h = bh & 7;
    const int q0 = qt * 128;
    const int w = t >> 6, ln = t & 63, l15 = ln & 15, quad = ln >> 4;

    // stage rowbias tile [128][32] bf16
    {
        int row = t >> 1, half = t & 1;
        const bf16* src = rowbias + ((size_t)bh * 1024 + q0 + row) * 32 + half * 16;
        *(bf16x8*)&rowbL[row][half * 16]     = *(const bf16x8*)src;
        *(bf16x8*)&rowbL[row][half * 16 + 8] = *(const bf16x8*)(src + 8);
    }

    // Q fragments (global -> regs)
    bf16x8 aq[2][2];
    #pragma unroll
    for (int mt = 0; mt < 2; ++mt) {
        const bf16* qp = qb + ((size_t)bh * 1024 + q0 + w * 32 + mt * 16 + l15) * 64;
        aq[mt][0] = *(const bf16x8*)(qp + quad * 8);
        aq[mt][1] = *(const bf16x8*)(qp + 32 + quad * 8);
    }

    // col-bias (global -> regs)
    float cbv[2][4][2];
    #pragma unroll
    for (int mt = 0; mt < 2; ++mt)
        #pragma unroll
        for (int r = 0; r < 4; ++r) {
            const bf16* cp = colbias + ((size_t)bh * 1024 + q0 + w * 32 + mt * 16 + quad * 4 + r) * 32;
            cbv[mt][r][0] = (float)cp[l15];
            cbv[mt][r][1] = (float)cp[16 + l15];
        }

    const f32x4 z4 = {0.f, 0.f, 0.f, 0.f};
    f32x4 oacc[2][4];
    float lsum[2][4];
    #pragma unroll
    for (int mt = 0; mt < 2; ++mt)
        #pragma unroll
        for (int r = 0; r < 4; ++r) { oacc[mt][r] = z4; lsum[mt][r] = 0.f; }

    bf16* Pw = &Ps[w][0][0];
    const bf16* kcbase = kb + (size_t)bh * 1024 * 64;
    const bf16* hcbase = htb + (size_t)b * 64 * 1024;

    for (int kc = 0; kc < 16; ++kc) {
        __syncthreads();
        // stage K chunk (row-major) + H^T chunk (d-major)
        {
            int row = t >> 2, c = (t & 3) << 4;
            const bf16* ksrc = kcbase + (size_t)(kc * 64 + row) * 64 + c;
            *(int4*)&Ks[row][c]     = *(const int4*)ksrc;
            *(int4*)&Ks[row][c + 8] = *(const int4*)(ksrc + 8);
            const bf16* hsrc = hcbase + (size_t)row * 1024 + kc * 64 + c;
            *(int4*)&Hts[row][c]     = *(const int4*)hsrc;
            *(int4*)&Hts[row][c + 8] = *(const int4*)(hsrc + 8);
        }
        __syncthreads();

        // ---- QK^T: 4 key-tiles x 2 k-halves x 2 m-tiles ----
        f32x4 sf[2][4];
        #pragma unroll
        for (int mt = 0; mt < 2; ++mt)
            #pragma unroll
            for (int kt = 0; kt < 4; ++kt) sf[mt][kt] = z4;
        #pragma unroll
        for (int kt = 0; kt < 4; ++kt) {
            bf16x8 bk0 = *(const bf16x8*)&Ks[kt * 16 + l15][quad * 8];
            bf16x8 bk1 = *(const bf16x8*)&Ks[kt * 16 + l15][32 + quad * 8];
            #pragma unroll
            for (int mt = 0; mt < 2; ++mt) {
                sf[mt][kt] = __builtin_amdgcn_mfma_f32_16x16x32_bf16(aq[mt][0], bk0, sf[mt][kt], 0, 0, 0);
                sf[mt][kt] = __builtin_amdgcn_mfma_f32_16x16x32_bf16(aq[mt][1], bk1, sf[mt][kt], 0, 0, 0);
            }
        }

        // ---- bias + exp + row-sum + swizzled P write ----
        #pragma unroll
        for (int mt = 0; mt < 2; ++mt)
            #pragma unroll
            for (int r = 0; r < 4; ++r) {
                int rl = w * 32 + mt * 16 + quad * 4 + r;
                bf16x2 rp = *(const bf16x2*)&rowbL[rl][kc * 2];
                float rb0 = (float)rp[0], rb1 = (float)rp[1];
                int prow = mt * 16 + quad * 4 + r;
                #pragma unroll
                for (int kt = 0; kt < 4; ++kt) {
                    float s = sf[mt][kt][r] + ((kt & 2) ? rb1 : rb0) + cbv[mt][r][kt & 1];
                    float p = __expf(s);
                    lsum[mt][r] += p;
                    Pw[prow * 72 + ((kt ^ quad) << 4) + l15] = (bf16)p;
                }
            }

        // ---- PV: A = P (swizzle-decoded), B = H^T ----
        bf16x8 ap[2][2];
        #pragma unroll
        for (int mt = 0; mt < 2; ++mt) {
            int prow = mt * 16 + l15;
            int key = l15 >> 2;                 // (row>>2)&3 for this row
            int off = (quad & 1) * 8;
            ap[mt][0] = *(const bf16x8*)&Pw[prow * 72 + ((((quad >> 1)) ^ key) << 4) + off];
            ap[mt][1] = *(const bf16x8*)&Pw[prow * 72 + (((2 + (quad >> 1)) ^ key) << 4) + off];
        }
        #pragma unroll
        for (int dt = 0; dt < 4; ++dt) {
            bf16x8 bh0 = *(const bf16x8*)&Hts[dt * 16 + l15][quad * 8];
            bf16x8 bh1 = *(const bf16x8*)&Hts[dt * 16 + l15][32 + quad * 8];
            #pragma unroll
            for (int mt = 0; mt < 2; ++mt) {
                oacc[mt][dt] = __builtin_amdgcn_mfma_f32_16x16x32_bf16(ap[mt][0], bh0, oacc[mt][dt], 0, 0, 0);
                oacc[mt][dt] = __builtin_amdgcn_mfma_f32_16x16x32_bf16(ap[mt][1], bh1, oacc[mt][dt], 0, 0, 0);
            }
        }
    }

    // ---- epilogue ----
    float inv[2][4];
    #pragma unroll
    for (int mt = 0; mt < 2; ++mt)
        #pragma unroll
        for (int r = 0; r < 4; ++r) {
            float v = lsum[mt][r];
            v += __shfl_xor(v, 1);
            v += __shfl_xor(v, 2);
            v += __shfl_xor(v, 4);
            v += __shfl_xor(v, 8);
            inv[mt][r] = 1.0f / v;
        }
    #pragma unroll
    for (int mt = 0; mt < 2; ++mt)
        #pragma unroll
        for (int dt = 0; dt < 4; ++dt)
            #pragma unroll
            for (int r = 0; r < 4; ++r) {
                int pos = q0 + w * 32 + mt * 16 + quad * 4 + r;
                mixed_ws[(((size_t)b * 1024 + pos) * 8 + h) * 64 + dt * 16 + l15] =
                    oacc[mt][dt][r] * inv[mt][r];
            }
}

// =====================================================================
// Kernel 4: output projection (fp32 VALU — precision-critical).
// =====================================================================
__global__ __launch_bounds__(256)
void out_proj_kernel(const float* __restrict__ mixed_ws,
                     const float* __restrict__ Wv, const float* __restrict__ bv,
                     float* __restrict__ out)
{
    __shared__ float mx[32][64];
    __shared__ float Wvs[64][65];

    const int t  = threadIdx.x;
    const int g0 = blockIdx.x * 32;
    const int tx = t & 63;
    const int ty = t >> 6;

    float acc[8] = {0.f,0.f,0.f,0.f,0.f,0.f,0.f,0.f};

    for (int oc = 0; oc < 8; ++oc) {
        __syncthreads();
        #pragma unroll
        for (int u = 0; u < 2; ++u) {
            int idx4 = t + 256 * u;
            int row = idx4 >> 4, c4 = (idx4 & 15) << 2;
            *(float4*)&mx[row][c4] =
                *(const float4*)(mixed_ws + (size_t)(g0 + row) * 512 + oc * 64 + c4);
        }
        {
            int row = t >> 2, off = (t & 3) << 4;
            const float* src = Wv + (size_t)row * 512 + oc * 64 + off;
            #pragma unroll
            for (int u = 0; u < 4; ++u) {
                float4 v = *(const float4*)(src + 4 * u);
                Wvs[row][off + 4*u + 0] = v.x; Wvs[row][off + 4*u + 1] = v.y;
                Wvs[row][off + 4*u + 2] = v.z; Wvs[row][off + 4*u + 3] = v.w;
            }
        }
        __syncthreads();

        #pragma unroll 8
        for (int oo = 0; oo < 64; ++oo) {
            float wv = Wvs[tx][oo];
            #pragma unroll
            for (int r = 0; r < 8; ++r)
                acc[r] += mx[ty * 8 + r][oo] * wv;
        }
    }

    float bias = bv[tx];
    #pragma unroll
    for (int r = 0; r < 8; ++r)
        out[(size_t)(g0 + ty * 8 + r) * 64 + tx] = acc[r] + bias;
}

// =====================================================================
extern "C" void kernel_launch(void* const* d_in, const int* in_sizes, int n_in,
                              void* d_out, int out_size, void* d_ws, size_t ws_size,
                              hipStream_t stream)
{
    const float* hid     = (const float*)d_in[0];
    const float* row_emb = (const float*)d_in[1];
    const float* col_emb = (const float*)d_in[2];
    const float* Wq      = (const float*)d_in[3];
    const float* bq      = (const float*)d_in[4];
    const float* Wk      = (const float*)d_in[5];
    const float* bk      = (const float*)d_in[6];
    const float* Wv      = (const float*)d_in[7];
    const float* bv      = (const float*)d_in[8];
    float* out = (float*)d_out;

    // ws: qb 8MB | kb 8MB | htb 1MB | rowbias 4MB | colbias 4MB | mixed 16MB = 41MB
    bf16* qb  = (bf16*)d_ws;
    bf16* kb  = qb + (size_t)64 * 1024 * 64;
    bf16* htb = kb + (size_t)64 * 1024 * 64;
    bf16* rowbias = htb + (size_t)8 * 64 * 1024;
    bf16* colbias = rowbias + (size_t)64 * 1024 * 32;
    float* mixed_ws = (float*)(colbias + (size_t)64 * 1024 * 32);

    qkproj_kernel<<<dim3(64, 4, 2), 256, 0, stream>>>(hid, Wq, bq, Wk, bk, qb, kb, htb);
    bias_kernel<<<dim3(64, 4), 256, 0, stream>>>(qb, row_emb, col_emb, rowbias, colbias);
    attn_kernel<<<dim3(8, 64), 256, 0, stream>>>(qb, kb, htb, rowbias, colbias, mixed_ws);
    out_proj_kernel<<<256, 256, 0, stream>>>(mixed_ws, Wv, bv, out);
}

// Round 4
// 135.074 us; speedup vs baseline: 3.4736x; 1.1655x over previous
//
#include <hip/hip_runtime.h>
#include <math.h>

typedef __bf16 bf16;
typedef bf16 bf16x2 __attribute__((ext_vector_type(2)));
typedef bf16 bf16x4 __attribute__((ext_vector_type(4)));
typedef bf16 bf16x8 __attribute__((ext_vector_type(8)));
typedef float f32x4 __attribute__((ext_vector_type(4)));

constexpr int CENTER = 31;

static __device__ __forceinline__ unsigned short f2bf_bits(float f) {
    bf16 b = (bf16)f;
    return __builtin_bit_cast(unsigned short, b);
}

// =====================================================================
// Kernel 1: Q/K projection GEMM via MFMA (bf16 in, bf16 out) + htb side-emit.
// grid = (64 pos-tiles x 4 out-tiles x {q,k}), block 256 (4 waves, 32 pos each).
// =====================================================================
__global__ __launch_bounds__(256)
void qkproj_kernel(const float* __restrict__ hid,
                   const float* __restrict__ Wq, const float* __restrict__ bq,
                   const float* __restrict__ Wk, const float* __restrict__ bk,
                   bf16* __restrict__ qb, bf16* __restrict__ kb,
                   bf16* __restrict__ htb)
{
    __shared__ __attribute__((aligned(16))) bf16 As[128][72];
    __shared__ __attribute__((aligned(16))) bf16 Bs[128][72];

    const int t  = threadIdx.x;
    const int pt = blockIdx.x;
    const int ot = blockIdx.y;
    const int z  = blockIdx.z;
    const float* W    = z ? Wk : Wq;
    const float* bias = z ? bk : bq;
    bf16* outp        = z ? kb : qb;
    const float scale = z ? 1.0f : 0.125f;
    const int p0 = pt * 128;
    const int b  = p0 >> 10;

    {
        int row = t >> 1, ch = (t & 1) * 32;
        const float4* asrc = (const float4*)(hid + (size_t)(p0 + row) * 64 + ch);
        const float4* bsrc = (const float4*)(W + (size_t)(ot * 128 + row) * 64 + ch);
        bf16 ta[32], tb[32];
        #pragma unroll
        for (int u = 0; u < 8; ++u) {
            float4 va = asrc[u], vb = bsrc[u];
            ta[4*u+0] = (bf16)va.x; ta[4*u+1] = (bf16)va.y;
            ta[4*u+2] = (bf16)va.z; ta[4*u+3] = (bf16)va.w;
            tb[4*u+0] = (bf16)vb.x; tb[4*u+1] = (bf16)vb.y;
            tb[4*u+2] = (bf16)vb.z; tb[4*u+3] = (bf16)vb.w;
        }
        #pragma unroll
        for (int u = 0; u < 4; ++u) {
            *(int4*)&As[row][ch + u * 8] = ((int4*)ta)[u];
            *(int4*)&Bs[row][ch + u * 8] = ((int4*)tb)[u];
        }
    }
    __syncthreads();

    if (ot == 0 && z == 0) {
        int d = t >> 2, ps = (t & 3) * 32;
        bf16* hdst = htb + ((size_t)b * 64 + d) * 1024 + (p0 & 1023) + ps;
        #pragma unroll
        for (int ii = 0; ii < 32; ii += 2) {
            ushort2 pk;
            pk.x = __builtin_bit_cast(unsigned short, As[ps + ii][d]);
            pk.y = __builtin_bit_cast(unsigned short, As[ps + ii + 1][d]);
            *(ushort2*)(hdst + ii) = pk;
        }
    }

    const int w = t >> 6, ln = t & 63, l15 = ln & 15, quad = ln >> 4;

    bf16x8 a[2][2];
    #pragma unroll
    for (int mt = 0; mt < 2; ++mt) {
        a[mt][0] = *(const bf16x8*)&As[w * 32 + mt * 16 + l15][quad * 8];
        a[mt][1] = *(const bf16x8*)&As[w * 32 + mt * 16 + l15][32 + quad * 8];
    }

    const f32x4 z4 = {0.f, 0.f, 0.f, 0.f};
    f32x4 acc[2][8];
    #pragma unroll
    for (int mt = 0; mt < 2; ++mt)
        #pragma unroll
        for (int nt = 0; nt < 8; ++nt) acc[mt][nt] = z4;

    #pragma unroll
    for (int nt = 0; nt < 8; ++nt) {
        bf16x8 b0 = *(const bf16x8*)&Bs[nt * 16 + l15][quad * 8];
        bf16x8 b1 = *(const bf16x8*)&Bs[nt * 16 + l15][32 + quad * 8];
        #pragma unroll
        for (int mt = 0; mt < 2; ++mt) {
            acc[mt][nt] = __builtin_amdgcn_mfma_f32_16x16x32_bf16(a[mt][0], b0, acc[mt][nt], 0, 0, 0);
            acc[mt][nt] = __builtin_amdgcn_mfma_f32_16x16x32_bf16(a[mt][1], b1, acc[mt][nt], 0, 0, 0);
        }
    }

    #pragma unroll
    for (int nt = 0; nt < 8; ++nt) {
        int o = ot * 128 + nt * 16 + l15;
        float bv = bias[o];
        int hh = o >> 6, d = o & 63;
        #pragma unroll
        for (int mt = 0; mt < 2; ++mt)
            #pragma unroll
            for (int r = 0; r < 4; ++r) {
                int pos = (p0 & 1023) + w * 32 + mt * 16 + quad * 4 + r;
                float val = (acc[mt][nt][r] + bv) * scale;
                outp[(((size_t)b * 8 + hh) * 1024 + pos) * 64 + d] = (bf16)val;
            }
    }
}

// =====================================================================
// Kernel 2: positional-bias precompute via MFMA (unchanged from R3).
// =====================================================================
__global__ __launch_bounds__(256)
void bias_kernel(const bf16* __restrict__ qb,
                 const float* __restrict__ row_emb, const float* __restrict__ col_emb,
                 bf16* __restrict__ rowbias, bf16* __restrict__ colbias)
{
    __shared__ __attribute__((aligned(16))) bf16 embRs[63][40];
    __shared__ __attribute__((aligned(16))) bf16 embCs[63][40];

    const int t  = threadIdx.x;
    const int bh = blockIdx.x;
    const int sg = blockIdx.y;

    for (int i = t; i < 2016; i += 256) embRs[i >> 5][i & 31] = (bf16)row_emb[i];
    for (int i = t; i < 2016; i += 256) embCs[i >> 5][i & 31] = (bf16)col_emb[i];
    __syncthreads();

    const int w = t >> 6, ln = t & 63, l15 = ln & 15, quad = ln >> 4;

    #pragma unroll
    for (int u = 0; u < 4; ++u) {
        int s = sg * 16 + u * 4 + w;
        bool cm = s >= 32;
        int ij = cm ? s - 32 : s;

        bf16x8 a[2];
        #pragma unroll
        for (int mt = 0; mt < 2; ++mt) {
            const bf16* ap = cm
                ? qb + ((size_t)bh * 1024 + (mt * 16 + l15) * 32 + ij) * 64 + 32 + quad * 8
                : qb + ((size_t)bh * 1024 + ij * 32 + mt * 16 + l15) * 64 + quad * 8;
            a[mt] = *(const bf16x8*)ap;
        }
        bf16* ob = cm ? colbias : rowbias;

        #pragma unroll
        for (int nt = 0; nt < 2; ++nt) {
            int erow = nt * 16 + l15 + CENTER - ij;
            bf16x8 bfrag = cm ? *(const bf16x8*)&embCs[erow][quad * 8]
                              : *(const bf16x8*)&embRs[erow][quad * 8];
            #pragma unroll
            for (int mt = 0; mt < 2; ++mt) {
                f32x4 c = {0.f, 0.f, 0.f, 0.f};
                c = __builtin_amdgcn_mfma_f32_16x16x32_bf16(a[mt], bfrag, c, 0, 0, 0);
                #pragma unroll
                for (int r = 0; r < 4; ++r) {
                    int ql = mt * 16 + quad * 4 + r;
                    int qrow = cm ? ql * 32 + ij : ij * 32 + ql;
                    ob[((size_t)bh * 1024 + qrow) * 32 + nt * 16 + l15] = (bf16)c[r];
                }
            }
        }
    }
}

// =====================================================================
// Kernel 3: MFMA flash attention, TRANSPOSED dataflow.
//   S^T = K·Q^T  (C-layout: lane holds 4 consecutive keys for one q=l15)
//   P stored row-per-q in LDS: packed b64 writes, aligned b128 B-frag reads
//   O^T = H^T·P^T; epilogue stores bf16 mixed.
// grid (8 q-tiles of 128, 64 bh), block 256 (4 waves x 32 q).
// =====================================================================
__global__ __launch_bounds__(256, 2)
void attn_kernel(const bf16* __restrict__ qb, const bf16* __restrict__ kb,
                 const bf16* __restrict__ htb,
                 const bf16* __restrict__ rowbias, const bf16* __restrict__ colbias,
                 bf16* __restrict__ mixedb)
{
    __shared__ __attribute__((aligned(16))) bf16 Ks[64][72];
    __shared__ __attribute__((aligned(16))) bf16 Hts[64][72];
    __shared__ __attribute__((aligned(16))) bf16 Pp[4][32][72];

    const int t  = threadIdx.x;
    const int qt = blockIdx.x;
    const int bh = blockIdx.y;
    const int b  = bh >> 3, h = bh & 7;
    const int q0 = qt * 128;
    const int w = t >> 6, ln = t & 63, l15 = ln & 15, quad = ln >> 4;

    // ---- loop-invariant register preloads (all from global) ----
    bf16x8 bq_[2][2];           // Q as B-operand: lane l15 = q, k = d
    float  cbv[2][2][4];        // col bias: [mt][key&16?][r]
    const bf16* rbp[2];         // row bias row pointers
    #pragma unroll
    for (int mt = 0; mt < 2; ++mt) {
        int qrow = q0 + w * 32 + mt * 16 + l15;
        const bf16* qp = qb + ((size_t)bh * 1024 + qrow) * 64;
        bq_[mt][0] = *(const bf16x8*)(qp + quad * 8);
        bq_[mt][1] = *(const bf16x8*)(qp + 32 + quad * 8);
        #pragma unroll
        for (int par = 0; par < 2; ++par) {
            bf16x4 cv = *(const bf16x4*)(colbias + ((size_t)bh * 1024 + qrow) * 32 + par * 16 + quad * 4);
            #pragma unroll
            for (int r = 0; r < 4; ++r) cbv[mt][par][r] = (float)cv[r];
        }
        rbp[mt] = rowbias + ((size_t)bh * 1024 + qrow) * 32;
    }

    const f32x4 z4 = {0.f, 0.f, 0.f, 0.f};
    f32x4 oacc[2][4];
    float lsum[2] = {0.f, 0.f};
    #pragma unroll
    for (int mt = 0; mt < 2; ++mt)
        #pragma unroll
        for (int dt = 0; dt < 4; ++dt) oacc[mt][dt] = z4;

    bf16* Pw = &Pp[w][0][0];
    const bf16* kcbase = kb + (size_t)bh * 1024 * 64;
    const bf16* hcbase = htb + (size_t)b * 64 * 1024;

    for (int kc = 0; kc < 16; ++kc) {
        __syncthreads();
        {
            int row = t >> 2, c = (t & 3) << 4;
            const bf16* ksrc = kcbase + (size_t)(kc * 64 + row) * 64 + c;
            *(int4*)&Ks[row][c]     = *(const int4*)ksrc;
            *(int4*)&Ks[row][c + 8] = *(const int4*)(ksrc + 8);
            const bf16* hsrc = hcbase + (size_t)row * 1024 + kc * 64 + c;
            *(int4*)&Hts[row][c]     = *(const int4*)hsrc;
            *(int4*)&Hts[row][c + 8] = *(const int4*)(hsrc + 8);
        }
        // row-bias for this chunk (2 key-rows), from global (L2-hot)
        float rb[2][2];
        #pragma unroll
        for (int mt = 0; mt < 2; ++mt) {
            bf16x2 rv = *(const bf16x2*)(rbp[mt] + kc * 2);
            rb[mt][0] = (float)rv[0]; rb[mt][1] = (float)rv[1];
        }
        __syncthreads();

        // ---- S^T = K·Q^T: A = K rows (lane=key), B = Q (lane=q) ----
        f32x4 sf[2][4];
        #pragma unroll
        for (int mt = 0; mt < 2; ++mt)
            #pragma unroll
            for (int kt = 0; kt < 4; ++kt) sf[mt][kt] = z4;
        #pragma unroll
        for (int kt = 0; kt < 4; ++kt) {
            bf16x8 aK0 = *(const bf16x8*)&Ks[kt * 16 + l15][quad * 8];
            bf16x8 aK1 = *(const bf16x8*)&Ks[kt * 16 + l15][32 + quad * 8];
            #pragma unroll
            for (int mt = 0; mt < 2; ++mt) {
                sf[mt][kt] = __builtin_amdgcn_mfma_f32_16x16x32_bf16(aK0, bq_[mt][0], sf[mt][kt], 0, 0, 0);
                sf[mt][kt] = __builtin_amdgcn_mfma_f32_16x16x32_bf16(aK1, bq_[mt][1], sf[mt][kt], 0, 0, 0);
            }
        }

        // ---- bias + exp + row-sum + packed P write (row q = l15) ----
        #pragma unroll
        for (int mt = 0; mt < 2; ++mt)
            #pragma unroll
            for (int kt = 0; kt < 4; ++kt) {
                float rbv = rb[mt][kt >> 1];
                ushort4 pk;
                float p0 = __expf(sf[mt][kt][0] + rbv + cbv[mt][kt & 1][0]);
                float p1 = __expf(sf[mt][kt][1] + rbv + cbv[mt][kt & 1][1]);
                float p2 = __expf(sf[mt][kt][2] + rbv + cbv[mt][kt & 1][2]);
                float p3 = __expf(sf[mt][kt][3] + rbv + cbv[mt][kt & 1][3]);
                lsum[mt] += (p0 + p1) + (p2 + p3);
                pk.x = f2bf_bits(p0); pk.y = f2bf_bits(p1);
                pk.z = f2bf_bits(p2); pk.w = f2bf_bits(p3);
                *(ushort4*)&Pw[(mt * 16 + l15) * 72 + kt * 16 + quad * 4] = pk;
            }

        // ---- O^T += H^T · P^T: A = Hts (lane=d), B = Pp (lane=q) ----
        bf16x8 bp[2][2];
        #pragma unroll
        for (int mt = 0; mt < 2; ++mt) {
            bp[mt][0] = *(const bf16x8*)&Pw[(mt * 16 + l15) * 72 + quad * 8];
            bp[mt][1] = *(const bf16x8*)&Pw[(mt * 16 + l15) * 72 + 32 + quad * 8];
        }
        #pragma unroll
        for (int dt = 0; dt < 4; ++dt) {
            bf16x8 aH0 = *(const bf16x8*)&Hts[dt * 16 + l15][quad * 8];
            bf16x8 aH1 = *(const bf16x8*)&Hts[dt * 16 + l15][32 + quad * 8];
            #pragma unroll
            for (int mt = 0; mt < 2; ++mt) {
                oacc[mt][dt] = __builtin_amdgcn_mfma_f32_16x16x32_bf16(aH0, bp[mt][0], oacc[mt][dt], 0, 0, 0);
                oacc[mt][dt] = __builtin_amdgcn_mfma_f32_16x16x32_bf16(aH1, bp[mt][1], oacc[mt][dt], 0, 0, 0);
            }
        }
    }

    // ---- epilogue: reduce l over quads, normalize, store bf16 mixed ----
    float inv[2];
    #pragma unroll
    for (int mt = 0; mt < 2; ++mt) {
        float v = lsum[mt];
        v += __shfl_xor(v, 16);
        v += __shfl_xor(v, 32);
        inv[mt] = 1.0f / v;
    }
    #pragma unroll
    for (int mt = 0; mt < 2; ++mt) {
        int pos = q0 + w * 32 + mt * 16 + l15;
        bf16* mb = mixedb + ((size_t)b * 1024 + pos) * 512 + h * 64;
        #pragma unroll
        for (int dt = 0; dt < 4; ++dt) {
            ushort4 pk;
            pk.x = f2bf_bits(oacc[mt][dt][0] * inv[mt]);
            pk.y = f2bf_bits(oacc[mt][dt][1] * inv[mt]);
            pk.z = f2bf_bits(oacc[mt][dt][2] * inv[mt]);
            pk.w = f2bf_bits(oacc[mt][dt][3] * inv[mt]);
            *(ushort4*)(mb + dt * 16 + quad * 4) = pk;
        }
    }
}

// =====================================================================
// Kernel 4: output projection via MFMA (bf16 inputs, fp32 out).
//   out[pos][c] = mixed[pos][:] . Wv[c][:] + bv[c]
// grid 128 blocks (64 pos), block 256 (4 waves x 16 pos). A from global,
// B (Wv bf16) staged in LDS per 256-K half. Bias folded into acc init.
// =====================================================================
__global__ __launch_bounds__(256)
void out_proj_kernel(const bf16* __restrict__ mixedb,
                     const float* __restrict__ Wv, const float* __restrict__ bv,
                     float* __restrict__ out)
{
    __shared__ __attribute__((aligned(16))) bf16 Wvs[64][264];

    const int t  = threadIdx.x;
    const int p0 = blockIdx.x * 64;
    const int w = t >> 6, ln = t & 63, l15 = ln & 15, quad = ln >> 4;

    f32x4 acc[4];
    #pragma unroll
    for (int nt = 0; nt < 4; ++nt) {
        float bvv = bv[nt * 16 + l15];
        acc[nt] = (f32x4){bvv, bvv, bvv, bvv};
    }

    const bf16* arow = mixedb + (size_t)(p0 + w * 16 + l15) * 512;

    for (int half = 0; half < 2; ++half) {
        __syncthreads();
        // stage Wv[0:64][half*256 : half*256+256] as bf16
        {
            int c = t >> 2, seg = (t & 3) * 64;
            const float4* src = (const float4*)(Wv + (size_t)c * 512 + half * 256 + seg);
            #pragma unroll
            for (int u = 0; u < 16; ++u) {
                float4 v = src[u];
                bf16x4 pk = {(bf16)v.x, (bf16)v.y, (bf16)v.z, (bf16)v.w};
                *(bf16x4*)&Wvs[c][seg + u * 4] = pk;
            }
        }
        __syncthreads();

        #pragma unroll
        for (int kc = 0; kc < 8; ++kc) {
            bf16x8 a = *(const bf16x8*)(arow + half * 256 + kc * 32 + quad * 8);
            #pragma unroll
            for (int nt = 0; nt < 4; ++nt) {
                bf16x8 bfrag = *(const bf16x8*)&Wvs[nt * 16 + l15][kc * 32 + quad * 8];
                acc[nt] = __builtin_amdgcn_mfma_f32_16x16x32_bf16(a, bfrag, acc[nt], 0, 0, 0);
            }
        }
    }

    // store: lane l15 = c (per nt), rows = pos
    #pragma unroll
    for (int nt = 0; nt < 4; ++nt)
        #pragma unroll
        for (int r = 0; r < 4; ++r)
            out[(size_t)(p0 + w * 16 + quad * 4 + r) * 64 + nt * 16 + l15] = acc[nt][r];
}

// =====================================================================
extern "C" void kernel_launch(void* const* d_in, const int* in_sizes, int n_in,
                              void* d_out, int out_size, void* d_ws, size_t ws_size,
                              hipStream_t stream)
{
    const float* hid     = (const float*)d_in[0];
    const float* row_emb = (const float*)d_in[1];
    const float* col_emb = (const float*)d_in[2];
    const float* Wq      = (const float*)d_in[3];
    const float* bq      = (const float*)d_in[4];
    const float* Wk      = (const float*)d_in[5];
    const float* bk      = (const float*)d_in[6];
    const float* Wv      = (const float*)d_in[7];
    const float* bv      = (const float*)d_in[8];
    float* out = (float*)d_out;

    // ws: qb 8MB | kb 8MB | htb 1MB | rowbias 4MB | colbias 4MB | mixedb 8MB
    bf16* qb  = (bf16*)d_ws;
    bf16* kb  = qb + (size_t)64 * 1024 * 64;
    bf16* htb = kb + (size_t)64 * 1024 * 64;
    bf16* rowbias = htb + (size_t)8 * 64 * 1024;
    bf16* colbias = rowbias + (size_t)64 * 1024 * 32;
    bf16* mixedb  = colbias + (size_t)64 * 1024 * 32;

    qkproj_kernel<<<dim3(64, 4, 2), 256, 0, stream>>>(hid, Wq, bq, Wk, bk, qb, kb, htb);
    bias_kernel<<<dim3(64, 4), 256, 0, stream>>>(qb, row_emb, col_emb, rowbias, colbias);
    attn_kernel<<<dim3(8, 64), 256, 0, stream>>>(qb, kb, htb, rowbias, colbias, mixedb);
    out_proj_kernel<<<128, 256, 0, stream>>>(mixedb, Wv, bv, out);
}